// Round 9
// baseline (375.553 us; speedup 1.0000x reference)
//
#include <hip/hip_runtime.h>
#include <math.h>

typedef __attribute__((ext_vector_type(8))) short short8;
typedef __attribute__((ext_vector_type(4))) float f32x4;
typedef __attribute__((ext_vector_type(2))) float f32x2;
typedef __attribute__((ext_vector_type(4))) unsigned short u16x4;

#define EPSV 1e-7f
#define PI_2 1.57079632679489662f
#define NEG_BIG (-3.4e38f)

constexpr int B = 4, C = 256;
constexpr int GW = 50;
constexpr int PR = 2500, PP = 2560;              // real / padded 50x50
constexpr int CPP = C * PP;                      // 655,360
constexpr long long SPB = (long long)PP * PP;    // 6,553,600
constexpr int PS = PP * C;                       // partial slice
constexpr int ZT = 213176;                       // sum_l B*H_l*W_l

// ---- workspace float offsets ----
constexpr size_t OFF_ORI   = 0;                            // fp32 [4][256][2560]
constexpr size_t OFF_BSF   = OFF_ORI + (size_t)B * CPP;    // u16 [4][256][2560] (bf16)
constexpr size_t OFF_Z     = OFF_BSF + (size_t)B * CPP;    // fp32 [9][ZT]
constexpr size_t OFF_BASIC = OFF_Z + (size_t)9 * ZT;
constexpr size_t OFF_ROW   = OFF_BASIC + 213184;
constexpr size_t OFF_COL   = OFF_ROW + 1600;
constexpr size_t OFF_STATS = OFF_COL + 1600;
constexpr size_t OFF_RSUM  = OFF_STATS + 128;              // fp32 [4][2560]
constexpr size_t OFF_U16   = OFF_RSUM + 10240;
// ---- u16 offsets within u16 region ----
constexpr size_t U_ORIT = 0;                               // [4][2560][256]
constexpr size_t U_THT  = U_ORIT + (size_t)B * CPP;
constexpr size_t U_PHT  = U_THT  + (size_t)B * CPP;
constexpr size_t U_G    = U_PHT  + (size_t)B * CPP;        // [4][256][2560]
constexpr size_t U_YTT  = U_G    + (size_t)B * CPP;        // (unused, keeps layout)
constexpr size_t U_WB   = U_YTT  + (size_t)B * CPP;        // 4 x [256][256]

__device__ __forceinline__ unsigned short f2b(float x) {
    union { float f; unsigned u; } q{x};
    unsigned r = q.u + 0x7FFFu + ((q.u >> 16) & 1u);
    return (unsigned short)(r >> 16);
}
__device__ __forceinline__ float b2f(unsigned short u) {
    union { unsigned u; float f; } q{(unsigned)u << 16};
    return q.f;
}

// ---- ori_fe single-element body ----
__device__ __forceinline__ float orife_val(
    int idx, const float* __restrict__ x0, const float* __restrict__ x1,
    const float* __restrict__ x2, const float* __restrict__ x3,
    const float* __restrict__ x4)
{
    int p = idx % PP; int bc = idx / PP;
    if (p >= PR) return 0.0f;
    int y = p / GW, x = p % GW;
    const float* p0 = x0 + (size_t)bc * 40000;
    float m0 = NEG_BIG;
    #pragma unroll
    for (int dy = 0; dy < 4; dy++) {
        f32x4 r = *(const f32x4*)(p0 + (y * 4 + dy) * 200 + x * 4);
        m0 = fmaxf(m0, fmaxf(fmaxf(r[0], r[1]), fmaxf(r[2], r[3])));
    }
    const float* p1 = x1 + (size_t)bc * 10000;
    float m1 = fmaxf(fmaxf(p1[(y*2)*100 + x*2],   p1[(y*2)*100 + x*2+1]),
                     fmaxf(p1[(y*2+1)*100 + x*2], p1[(y*2+1)*100 + x*2+1]));
    float v2 = x2[(size_t)bc * 2500 + p];
    float v3 = x3[(size_t)bc * 625 + (y/2)*25 + (x/2)];
    int ry = (y * 13) / 50, rx = (x * 13) / 50;
    float v4 = x4[(size_t)bc * 169 + ry * 13 + rx];
    return (m0 + m1 + v2 + v3 + v4) * 0.2f;
}

// ================= k_pre: rowm | colm | wcvt | ctap(x2 px) | orife(x4) | rsum-zero ====
// ranges: [0,388) rowm, [388,395) colm, [395,1419) wcvt,
//         [1419,1838) ctap, [1838,4398) orife, [4398,4408) rsum zero
constexpr int ORIFE_T = 2560 * 256;

__global__ __launch_bounds__(256) void k_pre(
    const float* __restrict__ x0, const float* __restrict__ x1,
    const float* __restrict__ x2, const float* __restrict__ x3,
    const float* __restrict__ x4, const float* __restrict__ rc_w,
    const float* __restrict__ wth, const float* __restrict__ wph,
    const float* __restrict__ wg,  const float* __restrict__ wout,
    unsigned short* __restrict__ wb, float* __restrict__ ori,
    float* __restrict__ z, float* __restrict__ row, float* __restrict__ col,
    float* __restrict__ rowsum)
{
    __shared__ float wsm[C * 12];
    const int bx = blockIdx.x;
    const int tid = threadIdx.x;

    if (bx < 388) {
        // ---- row means: 4 rows/block, one per wave ----
        int rid = bx * 4 + (tid >> 6);
        int lane = tid & 63;
        int base, H; const float* x;
        if      (rid < 800)  { base = 0;    H = 200; x = x0; }
        else if (rid < 1200) { base = 800;  H = 100; x = x1; }
        else if (rid < 1400) { base = 1200; H = 50;  x = x2; }
        else if (rid < 1500) { base = 1400; H = 25;  x = x3; }
        else                 { base = 1500; H = 13;  x = x4; }
        int r = rid - base; int b = r / H, h = r - (r / H) * H;
        const float* xr = x + (size_t)b * C * H * H + (size_t)h * H;
        float s = 0.0f;
        for (int w = lane; w < H; w += 64) s += xr[w];
        #pragma unroll
        for (int off = 32; off > 0; off >>= 1) s += __shfl_down(s, off);
        if (lane == 0) row[rid] = s / (float)H;
    } else if (bx < 395) {
        // ---- col means ----
        int idx = (bx - 388) * 256 + tid;
        if (idx >= 1552) return;
        int base, H; const float* x;
        if      (idx < 800)  { base = 0;    H = 200; x = x0; }
        else if (idx < 1200) { base = 800;  H = 100; x = x1; }
        else if (idx < 1400) { base = 1200; H = 50;  x = x2; }
        else if (idx < 1500) { base = 1400; H = 25;  x = x3; }
        else                 { base = 1500; H = 13;  x = x4; }
        int r = idx - base; int b = r / H, w = r - (r / H) * H;
        const float* xc = x + (size_t)b * C * H * H + w;
        float s = 0.0f;
        int h = 0;
        for (; h + 3 < H; h += 4) {
            float a0 = xc[(size_t)h * H];
            float a1 = xc[(size_t)(h + 1) * H];
            float a2 = xc[(size_t)(h + 2) * H];
            float a3 = xc[(size_t)(h + 3) * H];
            s += (a0 + a1) + (a2 + a3);
        }
        for (; h < H; h++) s += xc[(size_t)h * H];
        col[idx] = s / (float)H;
    } else if (bx < 1419) {
        // ---- weight convert ----
        int idx = (bx - 395) * 256 + tid;
        int seg = idx >> 16, off = idx & 65535;
        const float* s = (seg == 0) ? wth : (seg == 1) ? wph : (seg == 2) ? wg : wout;
        wb[idx] = f2b(s[off]);
    } else if (bx < 1838) {
        // ---- conv3x3 pass1: 2 px/thread (f32x2), 8-wide channel batches ----
        int bxx = bx - 1419;
        int lvl, base, HW, PH, zb; const float* x;
        if      (bxx < 313) { lvl = 0; base = 0;   HW = 40000; PH = 20000; zb = 0;      x = x0; }
        else if (bxx < 392) { lvl = 1; base = 313; HW = 10000; PH = 5000;  zb = 160000; x = x1; }
        else if (bxx < 412) { lvl = 2; base = 392; HW = 2500;  PH = 1250;  zb = 200000; x = x2; }
        else if (bxx < 417) { lvl = 3; base = 412; HW = 625;   PH = 313;   zb = 210000; x = x3; }
        else                { lvl = 4; base = 417; HW = 169;   PH = 85;    zb = 212500; x = x4; }
        const bool alig = (HW & 1) == 0;

        const float* w9 = rc_w + (size_t)lvl * C * 9;
        for (int i = tid; i < C * 9; i += 256) wsm[(i / 9) * 12 + (i % 9)] = w9[i];
        __syncthreads();

        int idx = (bxx - base) * 256 + tid;
        if (idx >= B * PH) return;
        int b = idx / PH, pp = (idx - b * PH) * 2;
        bool has2 = (pp + 1 < HW);

        float acc0[9] = {}, acc1[9] = {};
        const float* xp = x + (size_t)b * C * HW + pp;
        for (int c0 = 0; c0 < C; c0 += 8) {
            float v0[8], v1[8];
            #pragma unroll
            for (int k = 0; k < 8; k++) {
                const float* a = xp + (size_t)(c0 + k) * HW;
                if (alig && has2) { f32x2 t = *(const f32x2*)a; v0[k] = t[0]; v1[k] = t[1]; }
                else { v0[k] = a[0]; v1[k] = has2 ? a[1] : 0.0f; }
            }
            #pragma unroll
            for (int k = 0; k < 8; k++) {
                const float* wc = &wsm[(c0 + k) * 12];
                f32x4 w0 = *(const f32x4*)wc;
                f32x4 w1 = *(const f32x4*)(wc + 4);
                float w8 = wc[8];
                acc0[0] += v0[k] * w0[0]; acc1[0] += v1[k] * w0[0];
                acc0[1] += v0[k] * w0[1]; acc1[1] += v1[k] * w0[1];
                acc0[2] += v0[k] * w0[2]; acc1[2] += v1[k] * w0[2];
                acc0[3] += v0[k] * w0[3]; acc1[3] += v1[k] * w0[3];
                acc0[4] += v0[k] * w1[0]; acc1[4] += v1[k] * w1[0];
                acc0[5] += v0[k] * w1[1]; acc1[5] += v1[k] * w1[1];
                acc0[6] += v0[k] * w1[2]; acc1[6] += v1[k] * w1[2];
                acc0[7] += v0[k] * w1[3]; acc1[7] += v1[k] * w1[3];
                acc0[8] += v0[k] * w8;    acc1[8] += v1[k] * w8;
            }
        }
        #pragma unroll
        for (int t = 0; t < 9; t++) {
            size_t o = (size_t)t * ZT + zb + (size_t)b * HW + pp;
            if (alig && has2) { f32x2 wv = {acc0[t], acc1[t]}; *(f32x2*)&z[o] = wv; }
            else { z[o] = acc0[t]; if (has2) z[o + 1] = acc1[t]; }
        }
    } else if (bx < 4398) {
        // ---- ori_fe gather: 4 outputs/thread ----
        int t0 = (bx - 1838) * 256 + tid;
        #pragma unroll
        for (int k = 0; k < 4; k++) {
            int idx = t0 + k * ORIFE_T;
            ori[idx] = orife_val(idx, x0, x1, x2, x3, x4);
        }
    } else {
        // ---- zero rowsum ----
        int idx = (bx - 4398) * 1024 + tid * 4;
        f32x4 zv = {0.0f, 0.0f, 0.0f, 0.0f};
        *(f32x4*)(rowsum + idx) = zv;
    }
}

// ================= transpose+convert: ori fp32 [b][c][p] -> u16 [b][p][c] =================
__global__ __launch_bounds__(256) void k_tcvt(const float* __restrict__ ori,
                                              unsigned short* __restrict__ ot)
{
    __shared__ unsigned short t[64][66];
    int p0 = blockIdx.x * 64, c0 = blockIdx.y * 64, b = blockIdx.z;
    int pp = threadIdx.x & 63, cb = threadIdx.x >> 6;
    #pragma unroll
    for (int i = 0; i < 16; i++) {
        int cc = cb * 16 + i;
        t[cc][pp] = f2b(ori[((size_t)b * C + c0 + cc) * PP + p0 + pp]);
    }
    __syncthreads();
    int cc2 = threadIdx.x & 63, pb = threadIdx.x >> 6;
    #pragma unroll
    for (int i = 0; i < 16; i++) {
        int pp2 = pb * 16 + i;
        ot[((size_t)b * PP + p0 + pp2) * C + c0 + cc2] = t[cc2][pp2];
    }
}

// ================= merged projections (th, ph, g) =================
constexpr int LDT = 40;

__global__ __launch_bounds__(256) void k_proj(
    const unsigned short* __restrict__ wb, const unsigned short* __restrict__ orit,
    const float* __restrict__ th_b, const float* __restrict__ ph_b,
    const float* __restrict__ g_b,
    unsigned short* __restrict__ tht, unsigned short* __restrict__ pht,
    unsigned short* __restrict__ gb)
{
    __shared__ __align__(16) unsigned short As[128 * LDT];
    __shared__ __align__(16) unsigned short Bs[128 * LDT];

    const int z = blockIdx.z;
    const int b = z / 3, wsel = z - b * 3;
    const bool tp = (wsel < 2);
    const unsigned short* A = tp ? (orit + (size_t)b * CPP) : (wb + 131072);
    const unsigned short* Bm = tp ? (wb + wsel * 65536) : (orit + (size_t)b * CPP);
    const float* bias = (wsel == 0) ? th_b : (wsel == 1) ? ph_b : g_b;

    const int m0 = (tp ? blockIdx.x : blockIdx.y) * 128;
    const int n0 = (tp ? blockIdx.y : blockIdx.x) * 128;
    const int tid = threadIdx.x;
    const int lane = tid & 63, w = tid >> 6;
    const int wm = (w & 1) * 64, wn = (w >> 1) * 64;
    const int fr = lane & 15, fq = lane >> 4;

    f32x4 acc[4][4] = {};
    for (int k0 = 0; k0 < 256; k0 += 32) {
        #pragma unroll
        for (int l = 0; l < 2; l++) {
            int li = tid + l * 256;
            int rr = li >> 2, kc = li & 3;
            short8 va = *(const short8*)(A  + (size_t)(m0 + rr) * 256 + k0 + kc * 8);
            short8 vb = *(const short8*)(Bm + (size_t)(n0 + rr) * 256 + k0 + kc * 8);
            *(short8*)&As[rr * LDT + kc * 8] = va;
            *(short8*)&Bs[rr * LDT + kc * 8] = vb;
        }
        __syncthreads();
        short8 af[4], bf[4];
        #pragma unroll
        for (int i = 0; i < 4; i++)
            af[i] = *(const short8*)&As[(wm + i * 16 + fr) * LDT + fq * 8];
        #pragma unroll
        for (int j = 0; j < 4; j++)
            bf[j] = *(const short8*)&Bs[(wn + j * 16 + fr) * LDT + fq * 8];
        #pragma unroll
        for (int i = 0; i < 4; i++)
            #pragma unroll
            for (int j = 0; j < 4; j++)
                acc[i][j] = __builtin_amdgcn_mfma_f32_16x16x32_bf16(
                    af[i], bf[j], acc[i][j], 0, 0, 0);
        __syncthreads();
    }

    unsigned short* dst = (wsel == 0) ? tht : (wsel == 1) ? pht : gb;
    dst += (size_t)b * CPP;
    #pragma unroll
    for (int i = 0; i < 4; i++) {
        #pragma unroll
        for (int r = 0; r < 4; r++) {
            int gm = m0 + wm + i * 16 + fq * 4 + r;
            #pragma unroll
            for (int j = 0; j < 4; j++) {
                int gn = n0 + wn + j * 16 + fr;
                float v = acc[i][j][r] + (tp ? bias[gn] : bias[gm]);
                if (!tp && gn >= PR) v = 0.0f;
                size_t off = tp ? ((size_t)gm * 256 + gn) : ((size_t)gm * PP + gn);
                dst[off] = f2b(v);
            }
        }
    }
}

// ================= generic bf16 MFMA GEMM: C = A[M][K] * B[N][K]^T =================
// OutExp: write exp(v) bf16 (cols>=PR -> 0) and atomicAdd per-row exp sums into rowsum.
// BParts: B staged from two fp32 partial slices (parts, parts+PS), scaled by 1/rowsum.
template<bool AddBias, bool AddRes, bool OutBf, bool OutExp, bool BParts>
__global__ __launch_bounds__(256) void k_bgemm(
    const unsigned short* __restrict__ A, const unsigned short* __restrict__ Bm,
    const float* __restrict__ bias, const float* __restrict__ res,
    void* __restrict__ Cout, int K, int lda, int ldb, int ldc,
    long long sA, long long sB, long long sC, long long sR,
    int nsplit, long long sK,
    float* __restrict__ rowsum, const float* __restrict__ parts)
{
    __shared__ __align__(16) unsigned short As[128 * LDT];
    __shared__ __align__(16) unsigned short Bs[128 * LDT];

    const int z = blockIdx.z;
    const int bz = z / nsplit, ks = z - bz * nsplit;
    A  += (size_t)sA * bz + (size_t)sK * ks;
    Bm += (size_t)sB * bz + (size_t)sK * ks;

    const int m0 = blockIdx.y * 128, n0 = blockIdx.x * 128;
    const int tid = threadIdx.x;
    const int lane = tid & 63, w = tid >> 6;
    const int wm = (w & 1) * 64, wn = (w >> 1) * 64;
    const int fr = lane & 15, fq = lane >> 4;

    float inv0 = 0.0f, inv1 = 0.0f;
    const float* pbase = nullptr;
    if constexpr (BParts) {
        pbase = parts + (size_t)(bz * 2) * PS;
        inv0 = 1.0f / rowsum[(size_t)bz * PP + n0 + (tid >> 2)];
        inv1 = 1.0f / rowsum[(size_t)bz * PP + n0 + ((tid + 256) >> 2)];
    }

    f32x4 acc[4][4] = {};
    for (int k0 = 0; k0 < K; k0 += 32) {
        #pragma unroll
        for (int l = 0; l < 2; l++) {
            int li = tid + l * 256;
            int rr = li >> 2, kc = li & 3;
            short8 va = *(const short8*)(A + (size_t)(m0 + rr) * lda + k0 + kc * 8);
            short8 vb;
            if constexpr (BParts) {
                const float* pb = pbase + (size_t)(n0 + rr) * 256 + k0 + kc * 8;
                f32x4 a0 = *(const f32x4*)pb;
                f32x4 a1 = *(const f32x4*)(pb + 4);
                f32x4 b0 = *(const f32x4*)(pb + PS);
                f32x4 b1 = *(const f32x4*)(pb + PS + 4);
                float inv = l ? inv1 : inv0;
                #pragma unroll
                for (int e = 0; e < 4; e++) {
                    vb[e]     = (short)f2b((a0[e] + b0[e]) * inv);
                    vb[e + 4] = (short)f2b((a1[e] + b1[e]) * inv);
                }
            } else {
                vb = *(const short8*)(Bm + (size_t)(n0 + rr) * ldb + k0 + kc * 8);
            }
            *(short8*)&As[rr * LDT + kc * 8] = va;
            *(short8*)&Bs[rr * LDT + kc * 8] = vb;
        }
        __syncthreads();
        short8 af[4], bf[4];
        #pragma unroll
        for (int i = 0; i < 4; i++)
            af[i] = *(const short8*)&As[(wm + i * 16 + fr) * LDT + fq * 8];
        #pragma unroll
        for (int j = 0; j < 4; j++)
            bf[j] = *(const short8*)&Bs[(wn + j * 16 + fr) * LDT + fq * 8];
        #pragma unroll
        for (int i = 0; i < 4; i++)
            #pragma unroll
            for (int j = 0; j < 4; j++)
                acc[i][j] = __builtin_amdgcn_mfma_f32_16x16x32_bf16(
                    af[i], bf[j], acc[i][j], 0, 0, 0);
        __syncthreads();
    }

    float* Cf = (float*)Cout;
    unsigned short* Cb = (unsigned short*)Cout;
    const size_t co = (size_t)sC * z;
    const size_t ro = (size_t)sR * bz;
    float rsacc[4][4] = {};
    #pragma unroll
    for (int i = 0; i < 4; i++) {
        #pragma unroll
        for (int r = 0; r < 4; r++) {
            int gm = m0 + wm + i * 16 + fq * 4 + r;
            #pragma unroll
            for (int j = 0; j < 4; j++) {
                int gn = n0 + wn + j * 16 + fr;
                float v = acc[i][j][r];
                if constexpr (AddBias) v += bias[gm];
                if constexpr (AddRes)  v += res[ro + (size_t)gm * ldc + gn];
                size_t off = co + (size_t)gm * ldc + gn;
                if constexpr (OutExp) {
                    float e = (gn < PR) ? __expf(v) : 0.0f;
                    Cb[off] = f2b(e);
                    rsacc[i][r] += e;
                } else if constexpr (OutBf) {
                    Cb[off] = f2b(v);
                } else {
                    Cf[off] = v;
                }
            }
        }
    }
    if constexpr (OutExp) {
        #pragma unroll
        for (int i = 0; i < 4; i++)
            #pragma unroll
            for (int r = 0; r < 4; r++) {
                float s = rsacc[i][r];
                s += __shfl_xor(s, 1);
                s += __shfl_xor(s, 2);
                s += __shfl_xor(s, 4);
                s += __shfl_xor(s, 8);
                if (fr == 0)
                    atomicAdd(&rowsum[(size_t)bz * PP + m0 + wm + i * 16 + fq * 4 + r], s);
            }
    }
}

// ================= conv3x3 pass2 fused =================
template<int H, int ZB>
__device__ __forceinline__ void ccomb_impl(int idx, const float* __restrict__ z,
                                           float biasv, float* __restrict__ bas)
{
    constexpr int W = H, HW = H * W;
    int r = idx - ZB; int b = r / HW; int p = r - b * HW;
    int y = p / W, x = p - (p / W) * W;
    float acc = biasv;
    #pragma unroll
    for (int dy = 0; dy < 3; dy++) {
        int yy = y + dy - 1;
        if (yy < 0 || yy >= H) continue;
        #pragma unroll
        for (int dx = 0; dx < 3; dx++) {
            int xx = x + dx - 1;
            if (xx < 0 || xx >= W) continue;
            acc += z[(size_t)(dy * 3 + dx) * ZT + ZB + (size_t)b * HW + yy * W + xx];
        }
    }
    bas[idx] = fmaxf(acc, 0.0f);
}

__global__ __launch_bounds__(256) void k_ccomb_f(const float* __restrict__ z,
                                                 const float* __restrict__ rb,
                                                 float* __restrict__ bas)
{
    int idx = blockIdx.x * 256 + threadIdx.x;
    if (idx >= ZT) return;
    if      (idx < 160000) ccomb_impl<200, 0>     (idx, z, rb[0], bas);
    else if (idx < 200000) ccomb_impl<100, 160000>(idx, z, rb[1], bas);
    else if (idx < 210000) ccomb_impl<50,  200000>(idx, z, rb[2], bas);
    else if (idx < 212500) ccomb_impl<25,  210000>(idx, z, rb[3], bas);
    else                   ccomb_impl<13,  212500>(idx, z, rb[4], bas);
}

// ================= per-sample stats fused (block per (lvl,b)) =================
__global__ __launch_bounds__(256) void k_stats_f(
    const float* __restrict__ row, const float* __restrict__ col,
    const float* __restrict__ basic, float* __restrict__ stats)
{
    const int Ht[5]  = {200, 100, 50, 25, 13};
    const int ZBt[5] = {0, 160000, 200000, 210000, 212500};
    const int RBt[5] = {0, 800, 1200, 1400, 1500};
    int lvl = blockIdx.x >> 2, b = blockIdx.x & 3;
    int H = Ht[lvl], HW = H * H;
    const float* rw = row + RBt[lvl] + b * H;
    const float* cl = col + RBt[lvl] + b * H;
    const float* bb = basic + ZBt[lvl] + (size_t)b * HW;

    __shared__ float smn[256], smx[256];
    int t = threadIdx.x;
    float rmn, rmx, cmn, cmx, bmn, bmx;

    float mn = 3.4e38f, mx = NEG_BIG;
    for (int h = t; h < H; h += 256) { float v = rw[h]; mn = fminf(mn, v); mx = fmaxf(mx, v); }
    smn[t] = mn; smx[t] = mx; __syncthreads();
    for (int s = 128; s > 0; s >>= 1) { if (t < s) { smn[t] = fminf(smn[t], smn[t+s]); smx[t] = fmaxf(smx[t], smx[t+s]); } __syncthreads(); }
    rmn = smn[0]; rmx = smx[0]; __syncthreads();

    mn = 3.4e38f; mx = NEG_BIG;
    for (int w = t; w < H; w += 256) { float v = cl[w]; mn = fminf(mn, v); mx = fmaxf(mx, v); }
    smn[t] = mn; smx[t] = mx; __syncthreads();
    for (int s = 128; s > 0; s >>= 1) { if (t < s) { smn[t] = fminf(smn[t], smn[t+s]); smx[t] = fmaxf(smx[t], smx[t+s]); } __syncthreads(); }
    cmn = smn[0]; cmx = smx[0]; __syncthreads();

    mn = 3.4e38f; mx = NEG_BIG;
    for (int i = t; i < HW; i += 256) { float v = bb[i]; mn = fminf(mn, v); mx = fmaxf(mx, v); }
    smn[t] = mn; smx[t] = mx; __syncthreads();
    for (int s = 128; s > 0; s >>= 1) { if (t < s) { smn[t] = fminf(smn[t], smn[t+s]); smx[t] = fmaxf(smx[t], smx[t+s]); } __syncthreads(); }
    bmn = smn[0]; bmx = smx[0];

    if (t == 0) {
        float p1 = rmn * cmn, p2 = rmn * cmx, p3 = rmx * cmn, p4 = rmx * cmx;
        float amn = fminf(fminf(p1, p2), fminf(p3, p4));
        float amx = fmaxf(fmaxf(p1, p2), fmaxf(p3, p4));
        float* st = stats + lvl * 16 + b * 4;
        st[0] = amn; st[1] = amx; st[2] = bmn; st[3] = bmx;
    }
}

// ================= distance map fused (in-place over basic) =================
template<int H, int ZB, int RB, int LVL>
__device__ __forceinline__ void dist_impl(int idx, float* __restrict__ basic,
                                          const float* __restrict__ row,
                                          const float* __restrict__ col,
                                          const float* __restrict__ stats)
{
    constexpr int HW = H * H;
    int r = idx - ZB; int b = r / HW; int p = r - b * HW;
    int yh = p / H, xw = p - (p / H) * H;
    const float* st = stats + LVL * 16 + b * 4;
    float amn = st[0], amx = st[1], bmn = st[2], bmx = st[3];
    float an = (row[RB + b * H + yh] * col[RB + b * H + xw] - amn) / (amx - amn + EPSV);
    float bn = (basic[idx] - bmn) / (bmx - bmn + EPSV);
    basic[idx] = cosf((an - bn) * PI_2);
}

__global__ __launch_bounds__(256) void k_dist_f(float* __restrict__ basic,
                                                const float* __restrict__ row,
                                                const float* __restrict__ col,
                                                const float* __restrict__ stats)
{
    int idx = blockIdx.x * 256 + threadIdx.x;
    if (idx >= ZT) return;
    if      (idx < 160000) dist_impl<200, 0,      0,    0>(idx, basic, row, col, stats);
    else if (idx < 200000) dist_impl<100, 160000, 800,  1>(idx, basic, row, col, stats);
    else if (idx < 210000) dist_impl<50,  200000, 1200, 2>(idx, basic, row, col, stats);
    else if (idx < 212500) dist_impl<25,  210000, 1400, 3>(idx, basic, row, col, stats);
    else                   dist_impl<13,  212500, 1500, 4>(idx, basic, row, col, stats);
}

// ================= final: out = x + relu(bsf_resized * dist), batched =================
template<int LVL>
__device__ __forceinline__ void final_v4(int vid, const float* __restrict__ x,
                                         const unsigned short* __restrict__ bsf,
                                         const float* __restrict__ dist,
                                         float* __restrict__ out)
{
    constexpr int H = (LVL == 0) ? 200 : 100;
    constexpr int W = H, HW = H * W, Wv = W / 4;
    int xv = vid % Wv; int t = vid / Wv;
    int yh = t % H; t /= H; int c = t % C; int b = t / C;
    f32x4 xw4 = *(const f32x4*)(x + (size_t)vid * 4);
    f32x4 d4  = *(const f32x4*)(dist + (size_t)b * HW + yh * W + xv * 4);
    const unsigned short* bb = bsf + ((size_t)b * C + c) * PP;
    f32x4 o;
    if constexpr (LVL == 0) {
        float bv = b2f(bb[(yh >> 2) * GW + xv]);
        #pragma unroll
        for (int k = 0; k < 4; k++) o[k] = xw4[k] + fmaxf(bv * d4[k], 0.0f);
    } else {
        float bv0 = b2f(bb[(yh >> 1) * GW + 2 * xv]);
        float bv1 = b2f(bb[(yh >> 1) * GW + 2 * xv + 1]);
        o[0] = xw4[0] + fmaxf(bv0 * d4[0], 0.0f);
        o[1] = xw4[1] + fmaxf(bv0 * d4[1], 0.0f);
        o[2] = xw4[2] + fmaxf(bv1 * d4[2], 0.0f);
        o[3] = xw4[3] + fmaxf(bv1 * d4[3], 0.0f);
    }
    *(f32x4*)(out + (size_t)vid * 4) = o;
}

template<int LVL>
__device__ __forceinline__ void final_s(int idx, const float* __restrict__ x,
                                        const unsigned short* __restrict__ bsf,
                                        const float* __restrict__ dist,
                                        float* __restrict__ out)
{
    constexpr int H = (LVL == 2) ? 50 : (LVL == 3) ? 25 : 13;
    constexpr int W = H, HW = H * W;
    int xw = idx % W; int t = idx / W;
    int yh = t % H; t /= H; int c = t % C; int b = t / C;
    float d = dist[(size_t)b * HW + yh * W + xw];
    constexpr bool ident = (LVL == 2);
    int ry = ident ? yh : (yh * GW) / H;
    int rx = ident ? xw : (xw * GW) / W;
    float bv = b2f(bsf[((size_t)b * C + c) * PP + ry * GW + rx]);
    out[idx] = x[idx] + fmaxf(bv * d, 0.0f);
}

__global__ __launch_bounds__(256) void k_final_f(
    const float* __restrict__ x0, const float* __restrict__ x1,
    const float* __restrict__ x2, const float* __restrict__ x3,
    const float* __restrict__ x4, const unsigned short* __restrict__ bsf,
    const float* __restrict__ basic, float* __restrict__ out)
{
    int bx = blockIdx.x;
    int tid = threadIdx.x;
    if (bx < 8000) {
        int t0 = bx * 256 + tid;
        #pragma unroll
        for (int k = 0; k < 5; k++)
            final_v4<0>(t0 + k * 2048000, x0, bsf, basic, out);
    } else if (bx < 10000) {
        int t0 = (bx - 8000) * 256 + tid;
        #pragma unroll
        for (int k = 0; k < 5; k++)
            final_v4<1>(t0 + k * 512000, x1, bsf, basic + 160000, out + 40960000ull);
    } else if (bx < 12000) {
        int t0 = (bx - 10000) * 256 + tid;
        #pragma unroll
        for (int k = 0; k < 5; k++)
            final_s<2>(t0 + k * 512000, x2, bsf, basic + 200000, out + 51200000ull);
    } else if (bx < 12500) {
        int t0 = (bx - 12000) * 256 + tid;
        #pragma unroll
        for (int k = 0; k < 5; k++)
            final_s<3>(t0 + k * 128000, x3, bsf, basic + 210000, out + 53760000ull);
    } else {
        int t0 = (bx - 12500) * 256 + tid;
        #pragma unroll
        for (int k = 0; k < 4; k++)
            final_s<4>(t0 + k * 43264, x4, bsf, basic + 212500, out + 54400000ull);
    }
}

// ================= host =================
extern "C" void kernel_launch(void* const* d_in, const int* in_sizes, int n_in,
                              void* d_out, int out_size, void* d_ws, size_t ws_size,
                              hipStream_t stream)
{
    const float* x[5]; for (int i = 0; i < 5; i++) x[i] = (const float*)d_in[i];
    const float* rc_w  = (const float*)d_in[5];
    const float* rc_b  = (const float*)d_in[6];
    const float* g_b   = (const float*)d_in[8];
    const float* th_b  = (const float*)d_in[10];
    const float* ph_b  = (const float*)d_in[12];
    const float* out_b = (const float*)d_in[14];
    float* out = (float*)d_out;

    float* ws    = (float*)d_ws;
    float* ori   = ws + OFF_ORI;
    unsigned short* bsf = (unsigned short*)(ws + OFF_BSF);
    float* zbuf  = ws + OFF_Z;
    float* basic = ws + OFF_BASIC;
    float* rowb  = ws + OFF_ROW;
    float* colb  = ws + OFF_COL;
    float* stats = ws + OFF_STATS;
    float* rowsum = ws + OFF_RSUM;
    unsigned short* u16 = (unsigned short*)(ws + OFF_U16);
    unsigned short* orit = u16 + U_ORIT;
    unsigned short* tht  = u16 + U_THT;
    unsigned short* pht  = u16 + U_PHT;
    unsigned short* gb   = u16 + U_G;
    unsigned short* wb   = u16 + U_WB;
    unsigned short* wb_out = wb + 196608;

    // scratch in d_out (fully consumed before k_final_f writes)
    unsigned short* P_all = (unsigned short*)out;            // u16 [4][2560][2560]
    float* part = out + 4 * SPB;                             // fp32 [8][2560][256]

    // 1) pre: rowm + colm + wcvt + ctap(x2) + orife + rowsum-zero
    k_pre<<<4408, 256, 0, stream>>>(
        x[0], x[1], x[2], x[3], x[4], rc_w,
        (const float*)d_in[9], (const float*)d_in[11],
        (const float*)d_in[7], (const float*)d_in[13],
        wb, ori, zbuf, rowb, colb, rowsum);

    // 2) ori transpose+convert
    k_tcvt<<<dim3(PP / 64, C / 64, B), 256, 0, stream>>>(ori, orit);

    // 3) merged projections th/ph/g
    k_proj<<<dim3(20, 2, 12), 256, 0, stream>>>(wb, orit, th_b, ph_b, g_b, tht, pht, gb);

    // small per-level chain (independent of attention)
    k_ccomb_f<<<(ZT + 255) / 256, 256, 0, stream>>>(zbuf, rc_b, basic);
    k_stats_f<<<20, 256, 0, stream>>>(rowb, colb, basic, stats);
    k_dist_f<<<(ZT + 255) / 256, 256, 0, stream>>>(basic, rowb, colb, stats);

    // 4) P = exp(tht @ pht^T) with fused rowsum (S never materialized)
    dim3 gsc(PP / 128, PP / 128, B);
    k_bgemm<false, false, false, true, false><<<gsc, 256, 0, stream>>>(
        tht, pht, nullptr, nullptr, P_all, C, C, C, PP, CPP, CPP, SPB, 0, 1, 0,
        rowsum, nullptr);

    // 5) yt_unnorm = P @ g^T, split-K x2, fp32 partials
    dim3 gyt(C / 128, PP / 128, B * 2);
    k_bgemm<false, false, false, false, false><<<gyt, 256, 0, stream>>>(
        P_all, gb, nullptr, nullptr, part, PP / 2, PP, PP, C, SPB, CPP, PS, 0, 2, PP / 2,
        nullptr, nullptr);

    // 6) bsf = out_w @ (sum(parts)/rowsum) + out_b + ori  (reduce+normalize in staging)
    dim3 gbsf(PP / 128, C / 128, B);
    k_bgemm<true, true, true, false, true><<<gbsf, 256, 0, stream>>>(
        wb_out, (const unsigned short*)part, out_b, ori, bsf, C, C, 0, PP,
        0, 0, CPP, CPP, 1, 0, rowsum, part);

    // 7) finals
    k_final_f<<<12669, 256, 0, stream>>>(
        x[0], x[1], x[2], x[3], x[4], bsf, basic, out);
}

// Round 10
// 334.976 us; speedup vs baseline: 1.1211x; 1.1211x over previous
//
#include <hip/hip_runtime.h>
#include <math.h>

typedef __attribute__((ext_vector_type(8))) short short8;
typedef __attribute__((ext_vector_type(4))) float f32x4;
typedef __attribute__((ext_vector_type(4))) unsigned short u16x4;

#define EPSV 1e-7f
#define PI_2 1.57079632679489662f
#define NEG_BIG (-3.4e38f)

constexpr int B = 4, C = 256;
constexpr int GW = 50;
constexpr int PR = 2500, PP = 2560;              // real / padded 50x50
constexpr int CPP = C * PP;                      // 655,360
constexpr long long SPB = (long long)PP * PP;    // 6,553,600
constexpr int PS = PP * C;                       // partial slice
constexpr int ZT = 213176;                       // sum_l B*H_l*W_l

// ---- workspace float offsets ----
constexpr size_t OFF_ORI   = 0;                            // fp32 [4][256][2560]
constexpr size_t OFF_BSF   = OFF_ORI + (size_t)B * CPP;    // u16 [4][256][2560] (bf16)
constexpr size_t OFF_Z     = OFF_BSF + (size_t)B * CPP;    // fp32 [9][ZT]
constexpr size_t OFF_BASIC = OFF_Z + (size_t)9 * ZT;
constexpr size_t OFF_ROW   = OFF_BASIC + 213184;
constexpr size_t OFF_COL   = OFF_ROW + 1600;
constexpr size_t OFF_STATS = OFF_COL + 1600;
constexpr size_t OFF_RSUM  = OFF_STATS + 128;              // fp32 [4][2560]
constexpr size_t OFF_U16   = OFF_RSUM + 10240;
// ---- u16 offsets within u16 region ----
constexpr size_t U_ORIT = 0;                               // [4][2560][256]
constexpr size_t U_THT  = U_ORIT + (size_t)B * CPP;
constexpr size_t U_PHT  = U_THT  + (size_t)B * CPP;
constexpr size_t U_G    = U_PHT  + (size_t)B * CPP;        // [4][256][2560]
constexpr size_t U_YTT  = U_G    + (size_t)B * CPP;        // (unused, keeps layout)
constexpr size_t U_WB   = U_YTT  + (size_t)B * CPP;        // 4 x [256][256]

__device__ __forceinline__ unsigned short f2b(float x) {
    union { float f; unsigned u; } q{x};
    unsigned r = q.u + 0x7FFFu + ((q.u >> 16) & 1u);
    return (unsigned short)(r >> 16);
}
__device__ __forceinline__ float b2f(unsigned short u) {
    union { unsigned u; float f; } q{(unsigned)u << 16};
    return q.f;
}

// ---- ori_fe single-element body ----
__device__ __forceinline__ float orife_val(
    int idx, const float* __restrict__ x0, const float* __restrict__ x1,
    const float* __restrict__ x2, const float* __restrict__ x3,
    const float* __restrict__ x4)
{
    int p = idx % PP; int bc = idx / PP;
    if (p >= PR) return 0.0f;
    int y = p / GW, x = p % GW;
    const float* p0 = x0 + (size_t)bc * 40000;
    float m0 = NEG_BIG;
    #pragma unroll
    for (int dy = 0; dy < 4; dy++) {
        f32x4 r = *(const f32x4*)(p0 + (y * 4 + dy) * 200 + x * 4);
        m0 = fmaxf(m0, fmaxf(fmaxf(r[0], r[1]), fmaxf(r[2], r[3])));
    }
    const float* p1 = x1 + (size_t)bc * 10000;
    float m1 = fmaxf(fmaxf(p1[(y*2)*100 + x*2],   p1[(y*2)*100 + x*2+1]),
                     fmaxf(p1[(y*2+1)*100 + x*2], p1[(y*2+1)*100 + x*2+1]));
    float v2 = x2[(size_t)bc * 2500 + p];
    float v3 = x3[(size_t)bc * 625 + (y/2)*25 + (x/2)];
    int ry = (y * 13) / 50, rx = (x * 13) / 50;
    float v4 = x4[(size_t)bc * 169 + ry * 13 + rx];
    return (m0 + m1 + v2 + v3 + v4) * 0.2f;
}

// ================= k_pre: rowm | colm | wcvt | ctap(1px) | orife(x4) | rsum-zero ====
// ranges: [0,388) rowm, [388,395) colm, [395,1419) wcvt,
//         [1419,2254) ctap, [2254,4814) orife, [4814,4824) rsum zero
constexpr int ORIFE_T = 2560 * 256;

__global__ __launch_bounds__(256) void k_pre(
    const float* __restrict__ x0, const float* __restrict__ x1,
    const float* __restrict__ x2, const float* __restrict__ x3,
    const float* __restrict__ x4, const float* __restrict__ rc_w,
    const float* __restrict__ wth, const float* __restrict__ wph,
    const float* __restrict__ wg,  const float* __restrict__ wout,
    unsigned short* __restrict__ wb, float* __restrict__ ori,
    float* __restrict__ z, float* __restrict__ row, float* __restrict__ col,
    float* __restrict__ rowsum)
{
    __shared__ float wsm[C * 12];
    const int bx = blockIdx.x;
    const int tid = threadIdx.x;

    if (bx < 388) {
        // ---- row means: 4 rows/block, one per wave ----
        int rid = bx * 4 + (tid >> 6);
        int lane = tid & 63;
        int base, H; const float* x;
        if      (rid < 800)  { base = 0;    H = 200; x = x0; }
        else if (rid < 1200) { base = 800;  H = 100; x = x1; }
        else if (rid < 1400) { base = 1200; H = 50;  x = x2; }
        else if (rid < 1500) { base = 1400; H = 25;  x = x3; }
        else                 { base = 1500; H = 13;  x = x4; }
        int r = rid - base; int b = r / H, h = r - (r / H) * H;
        const float* xr = x + (size_t)b * C * H * H + (size_t)h * H;
        float s = 0.0f;
        for (int w = lane; w < H; w += 64) s += xr[w];
        #pragma unroll
        for (int off = 32; off > 0; off >>= 1) s += __shfl_down(s, off);
        if (lane == 0) row[rid] = s / (float)H;
    } else if (bx < 395) {
        // ---- col means: thread per (lvl,b,w), 4 load streams ----
        int idx = (bx - 388) * 256 + tid;
        if (idx >= 1552) return;
        int base, H; const float* x;
        if      (idx < 800)  { base = 0;    H = 200; x = x0; }
        else if (idx < 1200) { base = 800;  H = 100; x = x1; }
        else if (idx < 1400) { base = 1200; H = 50;  x = x2; }
        else if (idx < 1500) { base = 1400; H = 25;  x = x3; }
        else                 { base = 1500; H = 13;  x = x4; }
        int r = idx - base; int b = r / H, w = r - (r / H) * H;
        const float* xc = x + (size_t)b * C * H * H + w;
        float s = 0.0f;
        int h = 0;
        for (; h + 3 < H; h += 4) {
            float a0 = xc[(size_t)h * H];
            float a1 = xc[(size_t)(h + 1) * H];
            float a2 = xc[(size_t)(h + 2) * H];
            float a3 = xc[(size_t)(h + 3) * H];
            s += (a0 + a1) + (a2 + a3);
        }
        for (; h < H; h++) s += xc[(size_t)h * H];
        col[idx] = s / (float)H;
    } else if (bx < 1419) {
        // ---- weight convert: 4 x 256x256 ----
        int idx = (bx - 395) * 256 + tid;
        int seg = idx >> 16, off = idx & 65535;
        const float* s = (seg == 0) ? wth : (seg == 1) ? wph : (seg == 2) ? wg : wout;
        wb[idx] = f2b(s[off]);
    } else if (bx < 2254) {
        // ---- conv3x3 pass1: 1 px/thread, 8-wide channel batches (round-8 form) ----
        int bxx = bx - 1419;
        int lvl, base, HW, zb; const float* x;
        if      (bxx < 625) { lvl = 0; base = 0;   HW = 40000; zb = 0;      x = x0; }
        else if (bxx < 782) { lvl = 1; base = 625; HW = 10000; zb = 160000; x = x1; }
        else if (bxx < 822) { lvl = 2; base = 782; HW = 2500;  zb = 200000; x = x2; }
        else if (bxx < 832) { lvl = 3; base = 822; HW = 625;   zb = 210000; x = x3; }
        else                { lvl = 4; base = 832; HW = 169;   zb = 212500; x = x4; }

        const float* w9 = rc_w + (size_t)lvl * C * 9;
        for (int i = tid; i < C * 9; i += 256) wsm[(i / 9) * 12 + (i % 9)] = w9[i];
        __syncthreads();

        int idx = (bxx - base) * 256 + tid;
        if (idx >= B * HW) return;
        int b = idx / HW, p = idx - b * HW;

        float acc[9] = {};
        const float* xp = x + (size_t)b * C * HW + p;
        for (int c0 = 0; c0 < C; c0 += 8) {
            float v[8];
            #pragma unroll
            for (int k = 0; k < 8; k++) v[k] = xp[(size_t)(c0 + k) * HW];
            #pragma unroll
            for (int k = 0; k < 8; k++) {
                const float* wc = &wsm[(c0 + k) * 12];
                f32x4 w0 = *(const f32x4*)wc;
                f32x4 w1 = *(const f32x4*)(wc + 4);
                float w8 = wc[8];
                acc[0] += v[k] * w0[0]; acc[1] += v[k] * w0[1];
                acc[2] += v[k] * w0[2]; acc[3] += v[k] * w0[3];
                acc[4] += v[k] * w1[0]; acc[5] += v[k] * w1[1];
                acc[6] += v[k] * w1[2]; acc[7] += v[k] * w1[3];
                acc[8] += v[k] * w8;
            }
        }
        #pragma unroll
        for (int t = 0; t < 9; t++)
            z[(size_t)t * ZT + zb + idx] = acc[t];
    } else if (bx < 4814) {
        // ---- ori_fe gather: 4 outputs/thread, strided (coalesced) ----
        int t0 = (bx - 2254) * 256 + tid;
        #pragma unroll
        for (int k = 0; k < 4; k++) {
            int idx = t0 + k * ORIFE_T;
            ori[idx] = orife_val(idx, x0, x1, x2, x3, x4);
        }
    } else {
        // ---- zero rowsum ----
        int idx = (bx - 4814) * 1024 + tid * 4;
        f32x4 zv = {0.0f, 0.0f, 0.0f, 0.0f};
        *(f32x4*)(rowsum + idx) = zv;
    }
}

// ================= conv3x3 pass2 body =================
template<int H, int ZB>
__device__ __forceinline__ void ccomb_impl(int idx, const float* __restrict__ z,
                                           float biasv, float* __restrict__ bas)
{
    constexpr int W = H, HW = H * W;
    int r = idx - ZB; int b = r / HW; int p = r - b * HW;
    int y = p / W, x = p - (p / W) * W;
    float acc = biasv;
    #pragma unroll
    for (int dy = 0; dy < 3; dy++) {
        int yy = y + dy - 1;
        if (yy < 0 || yy >= H) continue;
        #pragma unroll
        for (int dx = 0; dx < 3; dx++) {
            int xx = x + dx - 1;
            if (xx < 0 || xx >= W) continue;
            acc += z[(size_t)(dy * 3 + dx) * ZT + ZB + (size_t)b * HW + yy * W + xx];
        }
    }
    bas[idx] = fmaxf(acc, 0.0f);
}

// ================= k_mid: tcvt | ccomb (one launch; both depend only on k_pre) ======
// ranges: [0,640) tcvt (40x4x4), [640,1473) ccomb
__global__ __launch_bounds__(256) void k_mid(
    const float* __restrict__ ori, unsigned short* __restrict__ ot,
    const float* __restrict__ z, const float* __restrict__ rb,
    float* __restrict__ bas)
{
    __shared__ unsigned short t[64][66];
    const int bx = blockIdx.x;
    const int tid = threadIdx.x;

    if (bx < 640) {
        // ---- transpose+convert: ori fp32 [b][c][p] -> u16 [b][p][c] ----
        int p0 = (bx % 40) * 64;
        int c0 = ((bx / 40) & 3) * 64;
        int b  = bx / 160;
        int pp = tid & 63, cb = tid >> 6;
        #pragma unroll
        for (int i = 0; i < 16; i++) {
            int cc = cb * 16 + i;
            t[cc][pp] = f2b(ori[((size_t)b * C + c0 + cc) * PP + p0 + pp]);
        }
        __syncthreads();
        int cc2 = tid & 63, pb = tid >> 6;
        #pragma unroll
        for (int i = 0; i < 16; i++) {
            int pp2 = pb * 16 + i;
            ot[((size_t)b * PP + p0 + pp2) * C + c0 + cc2] = t[cc2][pp2];
        }
    } else {
        int idx = (bx - 640) * 256 + tid;
        if (idx >= ZT) return;
        if      (idx < 160000) ccomb_impl<200, 0>     (idx, z, rb[0], bas);
        else if (idx < 200000) ccomb_impl<100, 160000>(idx, z, rb[1], bas);
        else if (idx < 210000) ccomb_impl<50,  200000>(idx, z, rb[2], bas);
        else if (idx < 212500) ccomb_impl<25,  210000>(idx, z, rb[3], bas);
        else                   ccomb_impl<13,  212500>(idx, z, rb[4], bas);
    }
}

// ================= merged projections (th, ph, g) =================
constexpr int LDT = 40;

__global__ __launch_bounds__(256) void k_proj(
    const unsigned short* __restrict__ wb, const unsigned short* __restrict__ orit,
    const float* __restrict__ th_b, const float* __restrict__ ph_b,
    const float* __restrict__ g_b,
    unsigned short* __restrict__ tht, unsigned short* __restrict__ pht,
    unsigned short* __restrict__ gb)
{
    __shared__ __align__(16) unsigned short As[128 * LDT];
    __shared__ __align__(16) unsigned short Bs[128 * LDT];

    const int z = blockIdx.z;
    const int b = z / 3, wsel = z - b * 3;
    const bool tp = (wsel < 2);
    const unsigned short* A = tp ? (orit + (size_t)b * CPP) : (wb + 131072);
    const unsigned short* Bm = tp ? (wb + wsel * 65536) : (orit + (size_t)b * CPP);
    const float* bias = (wsel == 0) ? th_b : (wsel == 1) ? ph_b : g_b;

    const int m0 = (tp ? blockIdx.x : blockIdx.y) * 128;
    const int n0 = (tp ? blockIdx.y : blockIdx.x) * 128;
    const int tid = threadIdx.x;
    const int lane = tid & 63, w = tid >> 6;
    const int wm = (w & 1) * 64, wn = (w >> 1) * 64;
    const int fr = lane & 15, fq = lane >> 4;

    f32x4 acc[4][4] = {};
    for (int k0 = 0; k0 < 256; k0 += 32) {
        #pragma unroll
        for (int l = 0; l < 2; l++) {
            int li = tid + l * 256;
            int rr = li >> 2, kc = li & 3;
            short8 va = *(const short8*)(A  + (size_t)(m0 + rr) * 256 + k0 + kc * 8);
            short8 vb = *(const short8*)(Bm + (size_t)(n0 + rr) * 256 + k0 + kc * 8);
            *(short8*)&As[rr * LDT + kc * 8] = va;
            *(short8*)&Bs[rr * LDT + kc * 8] = vb;
        }
        __syncthreads();
        short8 af[4], bf[4];
        #pragma unroll
        for (int i = 0; i < 4; i++)
            af[i] = *(const short8*)&As[(wm + i * 16 + fr) * LDT + fq * 8];
        #pragma unroll
        for (int j = 0; j < 4; j++)
            bf[j] = *(const short8*)&Bs[(wn + j * 16 + fr) * LDT + fq * 8];
        #pragma unroll
        for (int i = 0; i < 4; i++)
            #pragma unroll
            for (int j = 0; j < 4; j++)
                acc[i][j] = __builtin_amdgcn_mfma_f32_16x16x32_bf16(
                    af[i], bf[j], acc[i][j], 0, 0, 0);
        __syncthreads();
    }

    unsigned short* dst = (wsel == 0) ? tht : (wsel == 1) ? pht : gb;
    dst += (size_t)b * CPP;
    #pragma unroll
    for (int i = 0; i < 4; i++) {
        #pragma unroll
        for (int r = 0; r < 4; r++) {
            int gm = m0 + wm + i * 16 + fq * 4 + r;
            #pragma unroll
            for (int j = 0; j < 4; j++) {
                int gn = n0 + wn + j * 16 + fr;
                float v = acc[i][j][r] + (tp ? bias[gn] : bias[gm]);
                if (!tp && gn >= PR) v = 0.0f;
                size_t off = tp ? ((size_t)gm * 256 + gn) : ((size_t)gm * PP + gn);
                dst[off] = f2b(v);
            }
        }
    }
}

// ================= generic bf16 MFMA GEMM: C = A[M][K] * B[N][K]^T =================
// OutExp: write exp(v) bf16 (cols>=PR -> 0) + atomicAdd per-row exp sums into rowsum.
// BParts: B staged from two fp32 partial slices (parts, parts+PS), scaled by 1/rowsum.
template<bool AddBias, bool AddRes, bool OutBf, bool OutExp, bool BParts>
__global__ __launch_bounds__(256) void k_bgemm(
    const unsigned short* __restrict__ A, const unsigned short* __restrict__ Bm,
    const float* __restrict__ bias, const float* __restrict__ res,
    void* __restrict__ Cout, int K, int lda, int ldb, int ldc,
    long long sA, long long sB, long long sC, long long sR,
    int nsplit, long long sK,
    float* __restrict__ rowsum, const float* __restrict__ parts)
{
    __shared__ __align__(16) unsigned short As[128 * LDT];
    __shared__ __align__(16) unsigned short Bs[128 * LDT];

    const int z = blockIdx.z;
    const int bz = z / nsplit, ks = z - bz * nsplit;
    A  += (size_t)sA * bz + (size_t)sK * ks;
    Bm += (size_t)sB * bz + (size_t)sK * ks;

    const int m0 = blockIdx.y * 128, n0 = blockIdx.x * 128;
    const int tid = threadIdx.x;
    const int lane = tid & 63, w = tid >> 6;
    const int wm = (w & 1) * 64, wn = (w >> 1) * 64;
    const int fr = lane & 15, fq = lane >> 4;

    float inv0 = 0.0f, inv1 = 0.0f;
    const float* pbase = nullptr;
    if constexpr (BParts) {
        pbase = parts + (size_t)(bz * 2) * PS;
        inv0 = 1.0f / rowsum[(size_t)bz * PP + n0 + (tid >> 2)];
        inv1 = 1.0f / rowsum[(size_t)bz * PP + n0 + ((tid + 256) >> 2)];
    }

    f32x4 acc[4][4] = {};
    for (int k0 = 0; k0 < K; k0 += 32) {
        #pragma unroll
        for (int l = 0; l < 2; l++) {
            int li = tid + l * 256;
            int rr = li >> 2, kc = li & 3;
            short8 va = *(const short8*)(A + (size_t)(m0 + rr) * lda + k0 + kc * 8);
            short8 vb;
            if constexpr (BParts) {
                const float* pb = pbase + (size_t)(n0 + rr) * 256 + k0 + kc * 8;
                f32x4 a0 = *(const f32x4*)pb;
                f32x4 a1 = *(const f32x4*)(pb + 4);
                f32x4 b0 = *(const f32x4*)(pb + PS);
                f32x4 b1 = *(const f32x4*)(pb + PS + 4);
                float inv = l ? inv1 : inv0;
                #pragma unroll
                for (int e = 0; e < 4; e++) {
                    vb[e]     = (short)f2b((a0[e] + b0[e]) * inv);
                    vb[e + 4] = (short)f2b((a1[e] + b1[e]) * inv);
                }
            } else {
                vb = *(const short8*)(Bm + (size_t)(n0 + rr) * ldb + k0 + kc * 8);
            }
            *(short8*)&As[rr * LDT + kc * 8] = va;
            *(short8*)&Bs[rr * LDT + kc * 8] = vb;
        }
        __syncthreads();
        short8 af[4], bf[4];
        #pragma unroll
        for (int i = 0; i < 4; i++)
            af[i] = *(const short8*)&As[(wm + i * 16 + fr) * LDT + fq * 8];
        #pragma unroll
        for (int j = 0; j < 4; j++)
            bf[j] = *(const short8*)&Bs[(wn + j * 16 + fr) * LDT + fq * 8];
        #pragma unroll
        for (int i = 0; i < 4; i++)
            #pragma unroll
            for (int j = 0; j < 4; j++)
                acc[i][j] = __builtin_amdgcn_mfma_f32_16x16x32_bf16(
                    af[i], bf[j], acc[i][j], 0, 0, 0);
        __syncthreads();
    }

    float* Cf = (float*)Cout;
    unsigned short* Cb = (unsigned short*)Cout;
    const size_t co = (size_t)sC * z;
    const size_t ro = (size_t)sR * bz;
    float rsacc[4][4] = {};
    #pragma unroll
    for (int i = 0; i < 4; i++) {
        #pragma unroll
        for (int r = 0; r < 4; r++) {
            int gm = m0 + wm + i * 16 + fq * 4 + r;
            #pragma unroll
            for (int j = 0; j < 4; j++) {
                int gn = n0 + wn + j * 16 + fr;
                float v = acc[i][j][r];
                if constexpr (AddBias) v += bias[gm];
                if constexpr (AddRes)  v += res[ro + (size_t)gm * ldc + gn];
                size_t off = co + (size_t)gm * ldc + gn;
                if constexpr (OutExp) {
                    float e = (gn < PR) ? __expf(v) : 0.0f;
                    Cb[off] = f2b(e);
                    rsacc[i][r] += e;
                } else if constexpr (OutBf) {
                    Cb[off] = f2b(v);
                } else {
                    Cf[off] = v;
                }
            }
        }
    }
    if constexpr (OutExp) {
        #pragma unroll
        for (int i = 0; i < 4; i++)
            #pragma unroll
            for (int r = 0; r < 4; r++) {
                float s = rsacc[i][r];
                s += __shfl_xor(s, 1);
                s += __shfl_xor(s, 2);
                s += __shfl_xor(s, 4);
                s += __shfl_xor(s, 8);
                if (fr == 0)
                    atomicAdd(&rowsum[(size_t)bz * PP + m0 + wm + i * 16 + fq * 4 + r], s);
            }
    }
}

// ================= per-sample stats fused (block per (lvl,b)) =================
__global__ __launch_bounds__(256) void k_stats_f(
    const float* __restrict__ row, const float* __restrict__ col,
    const float* __restrict__ basic, float* __restrict__ stats)
{
    const int Ht[5]  = {200, 100, 50, 25, 13};
    const int ZBt[5] = {0, 160000, 200000, 210000, 212500};
    const int RBt[5] = {0, 800, 1200, 1400, 1500};
    int lvl = blockIdx.x >> 2, b = blockIdx.x & 3;
    int H = Ht[lvl], HW = H * H;
    const float* rw = row + RBt[lvl] + b * H;
    const float* cl = col + RBt[lvl] + b * H;
    const float* bb = basic + ZBt[lvl] + (size_t)b * HW;

    __shared__ float smn[256], smx[256];
    int t = threadIdx.x;
    float rmn, rmx, cmn, cmx, bmn, bmx;

    float mn = 3.4e38f, mx = NEG_BIG;
    for (int h = t; h < H; h += 256) { float v = rw[h]; mn = fminf(mn, v); mx = fmaxf(mx, v); }
    smn[t] = mn; smx[t] = mx; __syncthreads();
    for (int s = 128; s > 0; s >>= 1) { if (t < s) { smn[t] = fminf(smn[t], smn[t+s]); smx[t] = fmaxf(smx[t], smx[t+s]); } __syncthreads(); }
    rmn = smn[0]; rmx = smx[0]; __syncthreads();

    mn = 3.4e38f; mx = NEG_BIG;
    for (int w = t; w < H; w += 256) { float v = cl[w]; mn = fminf(mn, v); mx = fmaxf(mx, v); }
    smn[t] = mn; smx[t] = mx; __syncthreads();
    for (int s = 128; s > 0; s >>= 1) { if (t < s) { smn[t] = fminf(smn[t], smn[t+s]); smx[t] = fmaxf(smx[t], smx[t+s]); } __syncthreads(); }
    cmn = smn[0]; cmx = smx[0]; __syncthreads();

    mn = 3.4e38f; mx = NEG_BIG;
    for (int i = t; i < HW; i += 256) { float v = bb[i]; mn = fminf(mn, v); mx = fmaxf(mx, v); }
    smn[t] = mn; smx[t] = mx; __syncthreads();
    for (int s = 128; s > 0; s >>= 1) { if (t < s) { smn[t] = fminf(smn[t], smn[t+s]); smx[t] = fmaxf(smx[t], smx[t+s]); } __syncthreads(); }
    bmn = smn[0]; bmx = smx[0];

    if (t == 0) {
        float p1 = rmn * cmn, p2 = rmn * cmx, p3 = rmx * cmn, p4 = rmx * cmx;
        float amn = fminf(fminf(p1, p2), fminf(p3, p4));
        float amx = fmaxf(fmaxf(p1, p2), fmaxf(p3, p4));
        float* st = stats + lvl * 16 + b * 4;
        st[0] = amn; st[1] = amx; st[2] = bmn; st[3] = bmx;
    }
}

// ================= distance map fused (in-place over basic) =================
template<int H, int ZB, int RB, int LVL>
__device__ __forceinline__ void dist_impl(int idx, float* __restrict__ basic,
                                          const float* __restrict__ row,
                                          const float* __restrict__ col,
                                          const float* __restrict__ stats)
{
    constexpr int HW = H * H;
    int r = idx - ZB; int b = r / HW; int p = r - b * HW;
    int yh = p / H, xw = p - (p / H) * H;
    const float* st = stats + LVL * 16 + b * 4;
    float amn = st[0], amx = st[1], bmn = st[2], bmx = st[3];
    float an = (row[RB + b * H + yh] * col[RB + b * H + xw] - amn) / (amx - amn + EPSV);
    float bn = (basic[idx] - bmn) / (bmx - bmn + EPSV);
    basic[idx] = cosf((an - bn) * PI_2);
}

__global__ __launch_bounds__(256) void k_dist_f(float* __restrict__ basic,
                                                const float* __restrict__ row,
                                                const float* __restrict__ col,
                                                const float* __restrict__ stats)
{
    int idx = blockIdx.x * 256 + threadIdx.x;
    if (idx >= ZT) return;
    if      (idx < 160000) dist_impl<200, 0,      0,    0>(idx, basic, row, col, stats);
    else if (idx < 200000) dist_impl<100, 160000, 800,  1>(idx, basic, row, col, stats);
    else if (idx < 210000) dist_impl<50,  200000, 1200, 2>(idx, basic, row, col, stats);
    else if (idx < 212500) dist_impl<25,  210000, 1400, 3>(idx, basic, row, col, stats);
    else                   dist_impl<13,  212500, 1500, 4>(idx, basic, row, col, stats);
}

// ================= final: out = x + relu(bsf_resized * dist), batched =================
template<int LVL>
__device__ __forceinline__ void final_v4(int vid, const float* __restrict__ x,
                                         const unsigned short* __restrict__ bsf,
                                         const float* __restrict__ dist,
                                         float* __restrict__ out)
{
    constexpr int H = (LVL == 0) ? 200 : 100;
    constexpr int W = H, HW = H * W, Wv = W / 4;
    int xv = vid % Wv; int t = vid / Wv;
    int yh = t % H; t /= H; int c = t % C; int b = t / C;
    f32x4 xw4 = *(const f32x4*)(x + (size_t)vid * 4);
    f32x4 d4  = *(const f32x4*)(dist + (size_t)b * HW + yh * W + xv * 4);
    const unsigned short* bb = bsf + ((size_t)b * C + c) * PP;
    f32x4 o;
    if constexpr (LVL == 0) {
        float bv = b2f(bb[(yh >> 2) * GW + xv]);
        #pragma unroll
        for (int k = 0; k < 4; k++) o[k] = xw4[k] + fmaxf(bv * d4[k], 0.0f);
    } else {
        float bv0 = b2f(bb[(yh >> 1) * GW + 2 * xv]);
        float bv1 = b2f(bb[(yh >> 1) * GW + 2 * xv + 1]);
        o[0] = xw4[0] + fmaxf(bv0 * d4[0], 0.0f);
        o[1] = xw4[1] + fmaxf(bv0 * d4[1], 0.0f);
        o[2] = xw4[2] + fmaxf(bv1 * d4[2], 0.0f);
        o[3] = xw4[3] + fmaxf(bv1 * d4[3], 0.0f);
    }
    *(f32x4*)(out + (size_t)vid * 4) = o;
}

template<int LVL>
__device__ __forceinline__ void final_s(int idx, const float* __restrict__ x,
                                        const unsigned short* __restrict__ bsf,
                                        const float* __restrict__ dist,
                                        float* __restrict__ out)
{
    constexpr int H = (LVL == 2) ? 50 : (LVL == 3) ? 25 : 13;
    constexpr int W = H, HW = H * W;
    int xw = idx % W; int t = idx / W;
    int yh = t % H; t /= H; int c = t % C; int b = t / C;
    float d = dist[(size_t)b * HW + yh * W + xw];
    constexpr bool ident = (LVL == 2);
    int ry = ident ? yh : (yh * GW) / H;
    int rx = ident ? xw : (xw * GW) / W;
    float bv = b2f(bsf[((size_t)b * C + c) * PP + ry * GW + rx]);
    out[idx] = x[idx] + fmaxf(bv * d, 0.0f);
}

__global__ __launch_bounds__(256) void k_final_f(
    const float* __restrict__ x0, const float* __restrict__ x1,
    const float* __restrict__ x2, const float* __restrict__ x3,
    const float* __restrict__ x4, const unsigned short* __restrict__ bsf,
    const float* __restrict__ basic, float* __restrict__ out)
{
    int bx = blockIdx.x;
    int tid = threadIdx.x;
    if (bx < 8000) {
        int t0 = bx * 256 + tid;
        #pragma unroll
        for (int k = 0; k < 5; k++)
            final_v4<0>(t0 + k * 2048000, x0, bsf, basic, out);
    } else if (bx < 10000) {
        int t0 = (bx - 8000) * 256 + tid;
        #pragma unroll
        for (int k = 0; k < 5; k++)
            final_v4<1>(t0 + k * 512000, x1, bsf, basic + 160000, out + 40960000ull);
    } else if (bx < 12000) {
        int t0 = (bx - 10000) * 256 + tid;
        #pragma unroll
        for (int k = 0; k < 5; k++)
            final_s<2>(t0 + k * 512000, x2, bsf, basic + 200000, out + 51200000ull);
    } else if (bx < 12500) {
        int t0 = (bx - 12000) * 256 + tid;
        #pragma unroll
        for (int k = 0; k < 5; k++)
            final_s<3>(t0 + k * 128000, x3, bsf, basic + 210000, out + 53760000ull);
    } else {
        int t0 = (bx - 12500) * 256 + tid;
        #pragma unroll
        for (int k = 0; k < 4; k++)
            final_s<4>(t0 + k * 43264, x4, bsf, basic + 212500, out + 54400000ull);
    }
}

// ================= host =================
extern "C" void kernel_launch(void* const* d_in, const int* in_sizes, int n_in,
                              void* d_out, int out_size, void* d_ws, size_t ws_size,
                              hipStream_t stream)
{
    const float* x[5]; for (int i = 0; i < 5; i++) x[i] = (const float*)d_in[i];
    const float* rc_w  = (const float*)d_in[5];
    const float* rc_b  = (const float*)d_in[6];
    const float* g_b   = (const float*)d_in[8];
    const float* th_b  = (const float*)d_in[10];
    const float* ph_b  = (const float*)d_in[12];
    const float* out_b = (const float*)d_in[14];
    float* out = (float*)d_out;

    float* ws    = (float*)d_ws;
    float* ori   = ws + OFF_ORI;
    unsigned short* bsf = (unsigned short*)(ws + OFF_BSF);
    float* zbuf  = ws + OFF_Z;
    float* basic = ws + OFF_BASIC;
    float* rowb  = ws + OFF_ROW;
    float* colb  = ws + OFF_COL;
    float* stats = ws + OFF_STATS;
    float* rowsum = ws + OFF_RSUM;
    unsigned short* u16 = (unsigned short*)(ws + OFF_U16);
    unsigned short* orit = u16 + U_ORIT;
    unsigned short* tht  = u16 + U_THT;
    unsigned short* pht  = u16 + U_PHT;
    unsigned short* gb   = u16 + U_G;
    unsigned short* wb   = u16 + U_WB;
    unsigned short* wb_out = wb + 196608;

    // scratch in d_out (fully consumed before k_final_f writes)
    unsigned short* P_all = (unsigned short*)out;            // u16 [4][2560][2560]
    float* part = out + 4 * SPB;                             // fp32 [8][2560][256]

    // 1) pre: rowm + colm + wcvt + ctap(1px) + orife + rowsum-zero
    k_pre<<<4824, 256, 0, stream>>>(
        x[0], x[1], x[2], x[3], x[4], rc_w,
        (const float*)d_in[9], (const float*)d_in[11],
        (const float*)d_in[7], (const float*)d_in[13],
        wb, ori, zbuf, rowb, colb, rowsum);

    // 2) mid: ori transpose+convert | conv pass2 (one launch)
    k_mid<<<1473, 256, 0, stream>>>(ori, orit, zbuf, rc_b, basic);

    // 3) merged projections th/ph/g
    k_proj<<<dim3(20, 2, 12), 256, 0, stream>>>(wb, orit, th_b, ph_b, g_b, tht, pht, gb);

    // small per-level chain (independent of attention)
    k_stats_f<<<20, 256, 0, stream>>>(rowb, colb, basic, stats);
    k_dist_f<<<(ZT + 255) / 256, 256, 0, stream>>>(basic, rowb, colb, stats);

    // 4) P = exp(tht @ pht^T) with fused rowsum (S never materialized)
    dim3 gsc(PP / 128, PP / 128, B);
    k_bgemm<false, false, false, true, false><<<gsc, 256, 0, stream>>>(
        tht, pht, nullptr, nullptr, P_all, C, C, C, PP, CPP, CPP, SPB, 0, 1, 0,
        rowsum, nullptr);

    // 5) yt_unnorm = P @ g^T, split-K x2, fp32 partials
    dim3 gyt(C / 128, PP / 128, B * 2);
    k_bgemm<false, false, false, false, false><<<gyt, 256, 0, stream>>>(
        P_all, gb, nullptr, nullptr, part, PP / 2, PP, PP, C, SPB, CPP, PS, 0, 2, PP / 2,
        nullptr, nullptr);

    // 6) bsf = out_w @ (sum(parts)/rowsum) + out_b + ori  (reduce+normalize in staging)
    dim3 gbsf(PP / 128, C / 128, B);
    k_bgemm<true, true, true, false, true><<<gbsf, 256, 0, stream>>>(
        wb_out, (const unsigned short*)part, out_b, ori, bsf, C, C, 0, PP,
        0, 0, CPP, CPP, 1, 0, rowsum, part);

    // 7) finals
    k_final_f<<<12669, 256, 0, stream>>>(
        x[0], x[1], x[2], x[3], x[4], bsf, basic, out);
}